// Round 10
// baseline (210.648 us; speedup 1.0000x reference)
//
#include <hip/hip_runtime.h>
#include <math.h>

// ---- problem constants ----
#define BB    2
#define TT    16
#define TP    17          // T_ = T+1
#define HH_   24
#define WW_   24
#define HWW   576         // HH*WW
#define DD    128
#define NHH   4
#define MLPD_ 512
#define NPIX  18432       // B*T*HW
#define NTOK  19584       // B*T_*HW
#define SCALE 0.17677669529663688f   // 1/sqrt(32)
#define OUT0_SIZE 2506752            // B*T_*HW*D

typedef unsigned short u16;
typedef __bf16 bf16x8 __attribute__((ext_vector_type(8)));
typedef float f32x4 __attribute__((ext_vector_type(4)));

__device__ __forceinline__ u16 f2b(float f) {
  unsigned u = __float_as_uint(f);
  u += 0x7FFFu + ((u >> 16) & 1u);
  return (u16)(u >> 16);
}
__device__ __forceinline__ float blo(unsigned u) { return __uint_as_float(u << 16); }
__device__ __forceinline__ float bhi(unsigned u) { return __uint_as_float(u & 0xFFFF0000u); }
__device__ __forceinline__ float b2f(u16 u) { return __uint_as_float((unsigned)u << 16); }

__device__ __forceinline__ float dot8p(uint4 a, uint4 b) {
  float s = blo(a.x) * blo(b.x) + bhi(a.x) * bhi(b.x);
  s += blo(a.y) * blo(b.y) + bhi(a.y) * bhi(b.y);
  s += blo(a.z) * blo(b.z) + bhi(a.z) * bhi(b.z);
  s += blo(a.w) * blo(b.w) + bhi(a.w) * bhi(b.w);
  return s;
}
__device__ __forceinline__ float getp(const float4* P, int j) {
  float4 v = P[j >> 2];
  switch (j & 3) { case 0: return v.x; case 1: return v.y; case 2: return v.z; default: return v.w; }
}

__device__ __forceinline__ float wsum64(float v) {
#pragma unroll
  for (int o = 32; o > 0; o >>= 1) v += __shfl_xor(v, o, 64);
  return v;
}

// ---- pack weights/biases (blocks 0..1026) + CLS prep (blocks 1027..1029) ---- grid(1030) block(256)
__global__ void k_packprep(const float* w0, const float* w1, const float* w2, const float* w3,
                           const float* w4, const float* w5, const float* w6, const float* w7,
                           const float* w8, const float* w9,
                           const float* sbq, const float* sbk, const float* sbv,
                           const float* tbq, const float* tbk, const float* tbv,
                           const float* query, const float* ln_w, const float* ln_b,
                           u16* __restrict__ out, float* __restrict__ sb3, float* __restrict__ tb3,
                           u16* __restrict__ KCb, u16* __restrict__ VCb) {
  int bid = blockIdx.x, tid = threadIdx.x;
  if (bid < 1027) {
    int idx = bid * 256 + tid;
    if (idx < 262144) {
      if (idx < 131072) {
        int seg = idx >> 14, local = idx & 16383;
        const float* tbl[8] = {w0, w1, w2, w3, w4, w5, w6, w7};
        int nn = local >> 7, kk = local & 127;
        out[idx] = f2b(tbl[seg][(size_t)kk * 128 + nn]);
      } else if (idx < 196608) {
        int local = idx - 131072;
        int nn = local >> 7, kk = local & 127;
        out[idx] = f2b(w8[(size_t)kk * 512 + nn]);
      } else {
        int local = idx - 196608;
        int nn = local >> 9, kk = local & 511;
        out[idx] = f2b(w9[(size_t)kk * 128 + nn]);
      }
    } else if (idx < 262528) {
      int i = idx - 262144;
      sb3[i] = i < 128 ? sbq[i] : (i < 256 ? sbk[i - 128] : sbv[i - 256]);
    } else if (idx < 262912) {
      int i = idx - 262528;
      tb3[i] = i < 128 ? tbq[i] : (i < 256 ? tbk[i - 128] : tbv[i - 256]);
    }
    return;
  }
  __shared__ float part[2][DD];
  __shared__ float xr[DD];
  __shared__ float pk[2][DD], pv[2][DD];
  int r = bid - 1027;
  int c = tid >> 7, d = tid & 127;
  if (r < BB) {
    const float* base = query + (size_t)r * TP * HWW * DD + d;   // frame 0
    float s = 0.f;
    for (int hw = c * 288; hw < c * 288 + 288; ++hw) s += base[(size_t)hw * DD];
    part[c][d] = s;
    __syncthreads();
    if (tid < DD) part[0][tid] = (part[0][tid] + part[1][tid]) * (1.0f / HWW);
    __syncthreads();
    if (tid < DD) {
      float mean = 0.f;
      for (int i = 0; i < DD; i++) mean += part[0][i];
      mean *= (1.0f / DD);
      float var = 0.f;
      for (int i = 0; i < DD; i++) { float t = part[0][i] - mean; var += t * t; }
      var *= (1.0f / DD);
      xr[tid] = (part[0][tid] - mean) * rsqrtf(var + 1e-5f) * ln_w[tid] + ln_b[tid];
    }
  } else {
    if (tid < DD) xr[tid] = ln_b[tid];
  }
  __syncthreads();
  float sk = 0.f, sv = 0.f;
  for (int e = c * 64; e < c * 64 + 64; e++) {
    float xe = xr[e];
    sk += xe * w1[e * DD + d];   // w1 = sWk
    sv += xe * w2[e * DD + d];   // w2 = sWv
  }
  pk[c][d] = sk; pv[c][d] = sv;
  __syncthreads();
  if (tid < DD) {
    float k = pk[0][tid] + pk[1][tid] + sbk[tid];
    float v = pv[0][tid] + pv[1][tid] + sbv[tid];
    KCb[r * DD + tid] = f2b(k);
    VCb[r * DD + tid] = f2b(v);
  }
}

// ---- LayerNorm rows -> bf16 ---- grid(ceil(nrows/4)) block(256)
// mode 0: src rows; 1: spatial visual gather (src=query); 2: virtual-XB (aux=query for frame-0 rows);
// 3: MLP (aux=CLSA[2][128] for frame-0 rows).
__global__ void k_ln(const float* __restrict__ src, const float* __restrict__ aux,
                     u16* __restrict__ dst,
                     const float* __restrict__ w, const float* __restrict__ bb,
                     int nrows, int mode) {
  int wid = (blockIdx.x * blockDim.x + threadIdx.x) >> 6;
  int lane = threadIdx.x & 63;
  if (wid >= nrows) return;
  const float* sp;
  if (mode == 1) { int b2 = wid / (TT * HWW); int r = wid - b2 * (TT * HWW);
                   sp = src + ((size_t)b2 * TP * HWW + HWW + r) * DD; }
  else if (mode == 2) { int b2 = wid / (TP * HWW); int loc = wid - b2 * (TP * HWW);
                        sp = (loc < HWW ? aux : src) + (size_t)wid * DD; }
  else if (mode == 3) { int b2 = wid / (TP * HWW); int loc = wid - b2 * (TP * HWW);
                        sp = (loc < HWW) ? (aux + b2 * DD) : (src + (size_t)wid * DD); }
  else sp = src + (size_t)wid * DD;
  float x0 = sp[lane], x1 = sp[lane + 64];
  float mean = wsum64(x0 + x1) * (1.0f / DD);
  float d0 = x0 - mean, d1 = x1 - mean;
  float var = wsum64(d0 * d0 + d1 * d1) * (1.0f / DD);
  float inv = rsqrtf(var + 1e-5f);
  u16* dp = dst + (size_t)wid * DD;
  dp[lane]      = f2b(d0 * inv * w[lane] + bb[lane]);
  dp[lane + 64] = f2b(d1 * inv * w[lane + 64] + bb[lane + 64]);
}

// ---- MFMA bf16 GEMM, BM=64 BN=128, K=128. A staged in LDS (1 barrier);
// B fragments HOISTED from global into registers before the MFMA chain (issued pre-barrier
// so their latency overlaps the A-stage drain). No Bs, no extra barriers.
// outmode 1: scatter orow = b*T_*HW + HW + (r%(T*HW)).
// rm: 0 none; 1 resid[orow*ldc+c]; 2 virtual-XB resid (resid2=query for frame-0 rows).
__global__ __launch_bounds__(256) void k_gemm(
    const u16* __restrict__ A,
    const u16* __restrict__ Wt, const float* __restrict__ bias,
    float* __restrict__ Cf, u16* __restrict__ Cb, int ldc,
    const float* __restrict__ resid, const float* __restrict__ resid2,
    int outmode, int rm) {
  __shared__ __align__(16) u16 As[64 * 128];
  int tx = threadIdx.x;
  int row0 = blockIdx.x * 64, col0 = blockIdx.y * 128;
  int lane = tx & 63, wid = tx >> 6;

  // issue A staging (global -> LDS via regs)
#pragma unroll
  for (int t = 0; t < 4; t++) {
    int c = tx + t * 256;            // 0..1023
    int r = c >> 4, c16 = c & 15;
    int dst = (r * 256 + c16 * 16) ^ ((r & 7) << 4);
    *(uint4*)((char*)As + dst) = *(const uint4*)&A[(size_t)(row0 + r) * 128 + c16 * 8];
  }

  // hoist all 16 B fragments (L1/L2-resident weights); latency overlaps barrier drain
  bf16x8 bw[4][4];
#pragma unroll
  for (int kc = 0; kc < 4; kc++) {
    int ko = kc * 32 + (lane >> 4) * 8;
#pragma unroll
    for (int j = 0; j < 4; j++) {
      int rb = col0 + (wid & 1) * 64 + j * 16 + (lane & 15);
      bw[kc][j] = *(const bf16x8*)&Wt[(size_t)rb * 128 + ko];
    }
  }
  __syncthreads();

  // hoist all 8 A fragments from LDS
  bf16x8 aw[4][2];
#pragma unroll
  for (int kc = 0; kc < 4; kc++) {
    int kob = (kc * 32 + (lane >> 4) * 8) * 2;
#pragma unroll
    for (int i = 0; i < 2; i++) {
      int ra = (wid >> 1) * 32 + i * 16 + (lane & 15);
      aw[kc][i] = *(const bf16x8*)((const char*)As + ((ra * 256 + kob) ^ ((ra & 7) << 4)));
    }
  }

  f32x4 z = {0.f, 0.f, 0.f, 0.f};
  f32x4 acc[2][4];
#pragma unroll
  for (int i = 0; i < 2; i++)
#pragma unroll
    for (int j = 0; j < 4; j++) acc[i][j] = z;
#pragma unroll
  for (int kc = 0; kc < 4; kc++)
#pragma unroll
    for (int i = 0; i < 2; i++)
#pragma unroll
      for (int j = 0; j < 4; j++)
        acc[i][j] = __builtin_amdgcn_mfma_f32_16x16x32_bf16(aw[kc][i], bw[kc][j], acc[i][j], 0, 0, 0);

  int rbase = row0 + (wid >> 1) * 32 + (lane >> 4) * 4;
  int cbase = col0 + (wid & 1) * 64 + (lane & 15);
#pragma unroll
  for (int i = 0; i < 2; i++) {
#pragma unroll
    for (int e = 0; e < 4; e++) {
      int r = rbase + i * 16 + e;
      size_t orow = r;
      if (outmode == 1) { int b2 = r / (TT * HWW); int rr = r - b2 * (TT * HWW);
                          orow = (size_t)b2 * TP * HWW + HWW + rr; }
#pragma unroll
      for (int j = 0; j < 4; j++) {
        int c = cbase + j * 16;
        float v = acc[i][j][e] + bias[c];
        size_t oidx = orow * (size_t)ldc + c;
        if (rm == 1) v += resid[oidx];
        else if (rm == 2) { int b2 = (int)(orow / (TP * HWW)); int loc = (int)orow - b2 * (TP * HWW);
                            v += (loc < HWW ? resid2 : resid)[oidx]; }
        if (Cf) Cf[oidx] = v; else Cb[oidx] = f2b(v);
      }
    }
  }
}

// ---- fused MLP: out0 = resid + (gelu(A@W1+b1))@W2 + b2 ---- grid(306) block(256)
// A (64x128) + H (64x512) in LDS (80 KB -> 2 blocks/CU); W1/W2 fragments hoisted into
// register arrays per 128-block (one latency exposure per 32 MFMAs). 2 barriers total.
__global__ __launch_bounds__(256) void k_mlp(
    const u16* __restrict__ A,
    const u16* __restrict__ W1t, const float* __restrict__ b1,
    const u16* __restrict__ W2t, const float* __restrict__ b2,
    const float* __restrict__ X2, const float* __restrict__ CLSA,
    float* __restrict__ out0) {
  __shared__ __align__(16) u16 As[64 * 128];     // 16 KB
  __shared__ __align__(16) u16 Hs[64 * 512];     // 64 KB, row stride 1024B, swizzled
  int tx = threadIdx.x;
  int row0 = blockIdx.x * 64;
  int lane = tx & 63, wid = tx >> 6;
  f32x4 z = {0.f, 0.f, 0.f, 0.f};

  // stage A (64x128)
#pragma unroll
  for (int t = 0; t < 4; t++) {
    int c = tx + t * 256;
    int r = c >> 4, c16 = c & 15;
    int dst = (r * 256 + c16 * 16) ^ ((r & 7) << 4);
    *(uint4*)((char*)As + dst) = *(const uint4*)&A[(size_t)(row0 + r) * 128 + c16 * 8];
  }
  __syncthreads();

  // hoist A fragments once (invariant across nb)
  bf16x8 aw[4][2];
#pragma unroll
  for (int kc = 0; kc < 4; kc++) {
    int kob = (kc * 32 + (lane >> 4) * 8) * 2;
#pragma unroll
    for (int i = 0; i < 2; i++) {
      int ra = (wid >> 1) * 32 + i * 16 + (lane & 15);
      aw[kc][i] = *(const bf16x8*)((const char*)As + ((ra * 256 + kob) ^ ((ra & 7) << 4)));
    }
  }

  // ---- phase 1: H = gelu(A @ W1 + b1), 4 col-blocks of 128, no barriers ----
#pragma unroll 1
  for (int nb = 0; nb < 4; nb++) {
    bf16x8 bw[4][4];
#pragma unroll
    for (int kc = 0; kc < 4; kc++) {
      int ko = kc * 32 + (lane >> 4) * 8;
#pragma unroll
      for (int j = 0; j < 4; j++) {
        int rb = nb * 128 + (wid & 1) * 64 + j * 16 + (lane & 15);
        bw[kc][j] = *(const bf16x8*)&W1t[(size_t)rb * 128 + ko];
      }
    }
    f32x4 acc[2][4];
#pragma unroll
    for (int i = 0; i < 2; i++)
#pragma unroll
      for (int j = 0; j < 4; j++) acc[i][j] = z;
#pragma unroll
    for (int kc = 0; kc < 4; kc++)
#pragma unroll
      for (int i = 0; i < 2; i++)
#pragma unroll
        for (int j = 0; j < 4; j++)
          acc[i][j] = __builtin_amdgcn_mfma_f32_16x16x32_bf16(aw[kc][i], bw[kc][j], acc[i][j], 0, 0, 0);
    // gelu + write to Hs
    int rb0 = (wid >> 1) * 32 + (lane >> 4) * 4;
    int cb0 = nb * 128 + (wid & 1) * 64 + (lane & 15);
#pragma unroll
    for (int i = 0; i < 2; i++)
#pragma unroll
      for (int e = 0; e < 4; e++) {
        int hr = rb0 + i * 16 + e;
#pragma unroll
        for (int j = 0; j < 4; j++) {
          int hc = cb0 + j * 16;
          float v = acc[i][j][e] + b1[hc];
          v = 0.5f * v * (1.0f + erff(v * 0.70710678118654752f));
          *(u16*)((char*)Hs + ((hr * 1024 + hc * 2) ^ ((hr & 7) << 4))) = f2b(v);
        }
      }
  }
  __syncthreads();   // Hs complete

  // ---- phase 2: C = Hs @ W2 + b2 + resid, no barriers ----
  f32x4 acc2[2][4];
#pragma unroll
  for (int i = 0; i < 2; i++)
#pragma unroll
    for (int j = 0; j < 4; j++) acc2[i][j] = z;
#pragma unroll 1
  for (int kb = 0; kb < 4; kb++) {
    bf16x8 bw2[4][4];
#pragma unroll
    for (int kc = 0; kc < 4; kc++) {
      int kcol = kb * 128 + kc * 32 + (lane >> 4) * 8;
#pragma unroll
      for (int j = 0; j < 4; j++) {
        int rb = (wid & 1) * 64 + j * 16 + (lane & 15);
        bw2[kc][j] = *(const bf16x8*)&W2t[(size_t)rb * 512 + kcol];
      }
    }
    bf16x8 ah[4][2];
#pragma unroll
    for (int kc = 0; kc < 4; kc++) {
      int kcol = kb * 128 + kc * 32 + (lane >> 4) * 8;
#pragma unroll
      for (int i = 0; i < 2; i++) {
        int ra = (wid >> 1) * 32 + i * 16 + (lane & 15);
        ah[kc][i] = *(const bf16x8*)((const char*)Hs + ((ra * 1024 + kcol * 2) ^ ((ra & 7) << 4)));
      }
    }
#pragma unroll
    for (int kc = 0; kc < 4; kc++)
#pragma unroll
      for (int i = 0; i < 2; i++)
#pragma unroll
        for (int j = 0; j < 4; j++)
          acc2[i][j] = __builtin_amdgcn_mfma_f32_16x16x32_bf16(ah[kc][i], bw2[kc][j], acc2[i][j], 0, 0, 0);
  }

  int rbase = row0 + (wid >> 1) * 32 + (lane >> 4) * 4;
  int cbase = (wid & 1) * 64 + (lane & 15);
#pragma unroll
  for (int i = 0; i < 2; i++)
#pragma unroll
    for (int e = 0; e < 4; e++) {
      int r = rbase + i * 16 + e;
      int b2i = r / (TP * HWW); int loc = r - b2i * (TP * HWW);
#pragma unroll
      for (int j = 0; j < 4; j++) {
        int c = cbase + j * 16;
        float v = acc2[i][j][e] + b2[c];
        v += (loc < HWW) ? CLSA[b2i * DD + c] : X2[(size_t)r * DD + c];
        out0[(size_t)r * DD + c] = v;
      }
    }
}

// ---- spatial local-window attention: 32-lane group per (pixel, head) ---- grid(9216) block(256)
// FAITHFUL MASK BUG: kv col j (j<25) masked by kernel-pos-j validity (col0=CLS!, col j=neigh j-1);
// col 25 (neigh 24) never masked. Invalid neighbors use pad row = proj(LN(0)).
__global__ __launch_bounds__(256) void k_sattn(const u16* __restrict__ qkvb,
                                               const u16* __restrict__ KCb,
                                               const u16* __restrict__ VCb,
                                               u16* __restrict__ outb) {
  __shared__ float Ps[8][32];
  int tid = threadIdx.x;
  int g = tid >> 5, lj = tid & 31;
  int G = blockIdx.x * 8 + g;
  int n = G >> 2, h = G & 3;
  int f = n / HWW, hw = n - f * HWW;
  int hp = hw / WW_, wp = hw - hp * WW_;
  size_t FB = (size_t)f * HWW * 384;

  const u16* kp;
  bool masked;
  if (lj == 0) {
    kp = KCb + (n & 1) * DD + h * 32;
    masked = !(hp >= 2 && wp >= 2);
  } else {
    int k = lj - 1;
    int y = hp + k / 5 - 2, x = wp + k % 5 - 2;
    bool vok = ((unsigned)y < 24u) & ((unsigned)x < 24u) & (k < 25);
    kp = vok ? (qkvb + FB + (size_t)(y * WW_ + x) * 384 + 128 + h * 32)
             : (KCb + BB * DD + h * 32);
    if (lj < 25) { int ym = hp + lj / 5 - 2, xm = wp + lj % 5 - 2;
                   masked = !(((unsigned)ym < 24u) & ((unsigned)xm < 24u)); }
    else masked = false;
  }
  const uint4* q4p = (const uint4*)(qkvb + (size_t)n * 384 + h * 32);
  const uint4* k4p = (const uint4*)kp;
  float s = 0.f;
#pragma unroll
  for (int i = 0; i < 4; i++) s += dot8p(q4p[i], k4p[i]);

  float scr = masked ? -1e9f : s * SCALE;
  if (lj >= 26) scr = -1e30f;
  float mx = scr;
#pragma unroll
  for (int o = 16; o > 0; o >>= 1) mx = fmaxf(mx, __shfl_xor(mx, o, 32));
  float p = __expf(scr - mx);
  float sum = p;
#pragma unroll
  for (int o = 16; o > 0; o >>= 1) sum += __shfl_xor(sum, o, 32);
  Ps[g][lj] = p * (1.0f / sum);

  float4 P4[7];
#pragma unroll
  for (int i = 0; i < 7; i++) P4[i] = *(const float4*)&Ps[g][i * 4];

  float o = getp(P4, 0) * b2f(VCb[(n & 1) * DD + h * 32 + lj]);
#pragma unroll
  for (int k = 0; k < 25; k++) {
    int y = hp + k / 5 - 2, x = wp + k % 5 - 2;
    bool vok = ((unsigned)y < 24u) & ((unsigned)x < 24u);
    const u16* vp = vok ? (qkvb + FB + (size_t)(y * WW_ + x) * 384 + 256)
                        : (VCb + BB * DD);
    o += getp(P4, k + 1) * b2f(vp[h * 32 + lj]);
  }
  outb[(size_t)n * DD + h * 32 + lj] = f2b(o);
}

// ---- temporal attention, lane-local dots, bf16 QKV ---- grid(576) block(256)
__global__ __launch_bounds__(256) void k_tattn(const u16* __restrict__ qkv,
                                               u16* __restrict__ outb,
                                               float* __restrict__ logits) {
  __shared__ float Qs[8][TP][32];
  __shared__ float Ps[8][TP][17];
  int tid = threadIdx.x;
  int g = tid >> 5, lj = tid & 31;
  int s = blockIdx.x * 2 + (g >> 2);
  int h = g & 3;
  int b = s / HWW, hw = s - b * HWW;
  size_t base = ((size_t)b * TP * HWW + hw) * 384 + h * 32;
  const size_t TSTR = (size_t)HWW * 384;

  float kreg[32];
  {
    const uint4* k4 = (const uint4*)(qkv + base + (size_t)(lj < 17 ? lj : 16) * TSTR + 128);
#pragma unroll
    for (int i = 0; i < 4; i++) {
      uint4 u = k4[i];
      kreg[i * 8 + 0] = blo(u.x); kreg[i * 8 + 1] = bhi(u.x);
      kreg[i * 8 + 2] = blo(u.y); kreg[i * 8 + 3] = bhi(u.y);
      kreg[i * 8 + 4] = blo(u.z); kreg[i * 8 + 5] = bhi(u.z);
      kreg[i * 8 + 6] = blo(u.w); kreg[i * 8 + 7] = bhi(u.w);
    }
  }
  float vreg[TP];
#pragma unroll
  for (int t = 0; t < TP; t++) {
    Qs[g][t][lj] = b2f(qkv[base + (size_t)t * TSTR + lj]);
    vreg[t]      = b2f(qkv[base + (size_t)t * TSTR + 256 + lj]);
  }

  float* lp = logits + (size_t)s * (NHH * TP * TP) + (size_t)h * (TP * TP);
#pragma unroll 4
  for (int tq = 0; tq < TP; tq++) {
    const float4* qrow = (const float4*)&Qs[g][tq][0];
    float a0 = 0.f, a1 = 0.f, a2 = 0.f, a3 = 0.f;
#pragma unroll
    for (int d4 = 0; d4 < 8; d4++) {
      float4 q4 = qrow[d4];
      a0 += q4.x * kreg[d4 * 4 + 0];
      a1 += q4.y * kreg[d4 * 4 + 1];
      a2 += q4.z * kreg[d4 * 4 + 2];
      a3 += q4.w * kreg[d4 * 4 + 3];
    }
    float sc = ((a0 + a1) + (a2 + a3)) * SCALE;
    if (lj < 17) lp[tq * 17 + lj] = sc;
    float scm = (lj < 17) ? sc : -1e30f;
    float mx = scm;
#pragma unroll
    for (int o = 16; o > 0; o >>= 1) mx = fmaxf(mx, __shfl_xor(mx, o, 32));
    float p = __expf(scm - mx);
    float sum = p;
#pragma unroll
    for (int o = 16; o > 0; o >>= 1) sum += __shfl_xor(sum, o, 32);
    if (lj < 17) Ps[g][tq][lj] = p * (1.0f / sum);
  }
#pragma unroll 4
  for (int tq = 0; tq < TP; tq++) {
    const float* prow = &Ps[g][tq][0];
    float o = 0.f;
#pragma unroll
    for (int t = 0; t < TP; t++) o += prow[t] * vreg[t];
    size_t r = ((size_t)b * TP + tq) * HWW + hw;
    outb[r * DD + h * 32 + lj] = f2b(o);
  }
}

// ---- CLS average (frame 0 of X2) -> CLSA[2][128] ---- grid(2) block(256)
__global__ void k_clsavg(const float* __restrict__ x2, float* __restrict__ clsa) {
  __shared__ float part[2][DD];
  int b = blockIdx.x, tid = threadIdx.x;
  int c = tid >> 7, d = tid & 127;
  const float* base = x2 + (size_t)b * TP * HWW * DD;
  float s = 0.f;
  for (int hw = c * 288; hw < c * 288 + 288; ++hw) s += base[(size_t)hw * DD + d];
  part[c][d] = s;
  __syncthreads();
  if (tid < DD) clsa[b * DD + tid] = (part[0][tid] + part[1][tid]) * (1.0f / HWW);
}

extern "C" void kernel_launch(void* const* d_in, const int* in_sizes, int n_in,
                              void* d_out, int out_size, void* d_ws, size_t ws_size,
                              hipStream_t stream) {
  const float* query  = (const float*)d_in[0];
  const float* ln_s_w = (const float*)d_in[3];
  const float* ln_s_b = (const float*)d_in[4];
  const float* sWq = (const float*)d_in[5];  const float* sbq = (const float*)d_in[6];
  const float* sWk = (const float*)d_in[7];  const float* sbk = (const float*)d_in[8];
  const float* sWv = (const float*)d_in[9];  const float* sbv = (const float*)d_in[10];
  const float* sWo = (const float*)d_in[11]; const float* sbo = (const float*)d_in[12];
  const float* ln_t_w = (const float*)d_in[13];
  const float* ln_t_b = (const float*)d_in[14];
  const float* tWq = (const float*)d_in[15]; const float* tbq = (const float*)d_in[16];
  const float* tWk = (const float*)d_in[17]; const float* tbk = (const float*)d_in[18];
  const float* tWv = (const float*)d_in[19]; const float* tbv = (const float*)d_in[20];
  const float* tWo = (const float*)d_in[21]; const float* tbo = (const float*)d_in[22];
  const float* ln_m_w = (const float*)d_in[23];
  const float* ln_m_b = (const float*)d_in[24];
  const float* mW1 = (const float*)d_in[25]; const float* mb1 = (const float*)d_in[26];
  const float* mW2 = (const float*)d_in[27]; const float* mb2 = (const float*)d_in[28];

  float* ws = (float*)d_ws;
  u16*   QKVb = (u16*)ws;                            // bf16, NTOK*384
  u16*   S0b  = (u16*)(ws + 7520256);                // bf16, NTOK*128 (LN / attn outputs)
  float* XB   = ws + 8773632;                        // f32, NTOK*128 (visual rows only)
  float* X2   = ws + 11280384;                       // f32, NTOK*128
  u16*   WT   = (u16*)(ws + 13787136);               // bf16 packed weights (262,144)
  float* sb3  = ws + 13918208;                       // 384
  float* tb3  = ws + 13918592;                       // 384
  u16*   KCb  = (u16*)(ws + 13920000);               // 3*128 bf16
  u16*   VCb  = (u16*)(ws + 13920192);               // 3*128 bf16
  float* CLSA = ws + 13920384;                       // 2*128 f32

  float* out0   = (float*)d_out;
  float* logits = out0 + OUT0_SIZE;

  // 1. pack weights + CLS prep
  k_packprep<<<1030, 256, 0, stream>>>(sWq, sWk, sWv, sWo, tWq, tWk, tWv, tWo, mW1, mW2,
                                       sbq, sbk, sbv, tbq, tbk, tbv,
                                       query, ln_s_w, ln_s_b, WT, sb3, tb3, KCb, VCb);
  // 2. spatial LN (visual gather)
  k_ln<<<NPIX / 4, 256, 0, stream>>>(query, nullptr, S0b, ln_s_w, ln_s_b, NPIX, 1);
  // 3. spatial QKV
  k_gemm<<<dim3(NPIX / 64, 3), 256, 0, stream>>>(S0b, WT, sb3, nullptr, QKVb, 384,
                                                 nullptr, nullptr, 0, 0);
  // 4. spatial attention
  k_sattn<<<NPIX * NHH / 8, 256, 0, stream>>>(QKVb, KCb, VCb, S0b);
  // 5. sWo projection + query residual -> XB (visual rows, scattered)
  k_gemm<<<dim3(NPIX / 64, 1), 256, 0, stream>>>(S0b, WT + 49152, sbo, XB, nullptr, 128,
                                                 query, nullptr, 1, 1);
  // 6. temporal LN (virtual-XB)
  k_ln<<<NTOK / 4, 256, 0, stream>>>(XB, query, S0b, ln_t_w, ln_t_b, NTOK, 2);
  // 7. temporal QKV
  k_gemm<<<dim3(NTOK / 64, 3), 256, 0, stream>>>(S0b, WT + 65536, tb3, nullptr, QKVb, 384,
                                                 nullptr, nullptr, 0, 0);
  // 8. temporal attention (+ logits)
  k_tattn<<<BB * HWW / 2, 256, 0, stream>>>(QKVb, S0b, logits);
  // 9. tWo projection + virtual-XB residual -> X2
  k_gemm<<<dim3(NTOK / 64, 1), 256, 0, stream>>>(S0b, WT + 114688, tbo, X2, nullptr, 128,
                                                 XB, query, 0, 2);
  // 10. CLS average -> CLSA
  k_clsavg<<<2, 256, 0, stream>>>(X2, CLSA);
  // 11. MLP LN (frame-0 rows from CLSA)
  k_ln<<<NTOK / 4, 256, 0, stream>>>(X2, CLSA, S0b, ln_m_w, ln_m_b, NTOK, 3);
  // 12. fused MLP -> out0
  k_mlp<<<NTOK / 64, 256, 0, stream>>>(S0b, WT + 131072, mb1, WT + 196608, mb2,
                                       X2, CLSA, out0);
}

// Round 11
// 205.137 us; speedup vs baseline: 1.0269x; 1.0269x over previous
//
#include <hip/hip_runtime.h>
#include <math.h>

// ---- problem constants ----
#define BB    2
#define TT    16
#define TP    17          // T_ = T+1
#define HH_   24
#define WW_   24
#define HWW   576         // HH*WW
#define DD    128
#define NHH   4
#define MLPD_ 512
#define NPIX  18432       // B*T*HW
#define NTOK  19584       // B*T_*HW
#define SCALE 0.17677669529663688f   // 1/sqrt(32)
#define OUT0_SIZE 2506752            // B*T_*HW*D

typedef unsigned short u16;
typedef __bf16 bf16x8 __attribute__((ext_vector_type(8)));
typedef float f32x4 __attribute__((ext_vector_type(4)));

__device__ __forceinline__ u16 f2b(float f) {
  unsigned u = __float_as_uint(f);
  u += 0x7FFFu + ((u >> 16) & 1u);
  return (u16)(u >> 16);
}
__device__ __forceinline__ float blo(unsigned u) { return __uint_as_float(u << 16); }
__device__ __forceinline__ float bhi(unsigned u) { return __uint_as_float(u & 0xFFFF0000u); }
__device__ __forceinline__ float b2f(u16 u) { return __uint_as_float((unsigned)u << 16); }

__device__ __forceinline__ float dot8p(uint4 a, uint4 b) {
  float s = blo(a.x) * blo(b.x) + bhi(a.x) * bhi(b.x);
  s += blo(a.y) * blo(b.y) + bhi(a.y) * bhi(b.y);
  s += blo(a.z) * blo(b.z) + bhi(a.z) * bhi(b.z);
  s += blo(a.w) * blo(b.w) + bhi(a.w) * bhi(b.w);
  return s;
}
__device__ __forceinline__ float getp(const float4* P, int j) {
  float4 v = P[j >> 2];
  switch (j & 3) { case 0: return v.x; case 1: return v.y; case 2: return v.z; default: return v.w; }
}

__device__ __forceinline__ float wsum64(float v) {
#pragma unroll
  for (int o = 32; o > 0; o >>= 1) v += __shfl_xor(v, o, 64);
  return v;
}

// ---- pack weights/biases (blocks 0..1026) + CLS prep (blocks 1027..1029) ---- grid(1030) block(256)
__global__ void k_packprep(const float* w0, const float* w1, const float* w2, const float* w3,
                           const float* w4, const float* w5, const float* w6, const float* w7,
                           const float* w8, const float* w9,
                           const float* sbq, const float* sbk, const float* sbv,
                           const float* tbq, const float* tbk, const float* tbv,
                           const float* query, const float* ln_w, const float* ln_b,
                           u16* __restrict__ out, float* __restrict__ sb3, float* __restrict__ tb3,
                           u16* __restrict__ KCb, u16* __restrict__ VCb) {
  int bid = blockIdx.x, tid = threadIdx.x;
  if (bid < 1027) {
    int idx = bid * 256 + tid;
    if (idx < 262144) {
      if (idx < 131072) {
        int seg = idx >> 14, local = idx & 16383;
        const float* tbl[8] = {w0, w1, w2, w3, w4, w5, w6, w7};
        int nn = local >> 7, kk = local & 127;
        out[idx] = f2b(tbl[seg][(size_t)kk * 128 + nn]);
      } else if (idx < 196608) {
        int local = idx - 131072;
        int nn = local >> 7, kk = local & 127;
        out[idx] = f2b(w8[(size_t)kk * 512 + nn]);
      } else {
        int local = idx - 196608;
        int nn = local >> 9, kk = local & 511;
        out[idx] = f2b(w9[(size_t)kk * 128 + nn]);
      }
    } else if (idx < 262528) {
      int i = idx - 262144;
      sb3[i] = i < 128 ? sbq[i] : (i < 256 ? sbk[i - 128] : sbv[i - 256]);
    } else if (idx < 262912) {
      int i = idx - 262528;
      tb3[i] = i < 128 ? tbq[i] : (i < 256 ? tbk[i - 128] : tbv[i - 256]);
    }
    return;
  }
  __shared__ float part[2][DD];
  __shared__ float xr[DD];
  __shared__ float pk[2][DD], pv[2][DD];
  int r = bid - 1027;
  int c = tid >> 7, d = tid & 127;
  if (r < BB) {
    const float* base = query + (size_t)r * TP * HWW * DD + d;   // frame 0
    float s = 0.f;
    for (int hw = c * 288; hw < c * 288 + 288; ++hw) s += base[(size_t)hw * DD];
    part[c][d] = s;
    __syncthreads();
    if (tid < DD) part[0][tid] = (part[0][tid] + part[1][tid]) * (1.0f / HWW);
    __syncthreads();
    if (tid < DD) {
      float mean = 0.f;
      for (int i = 0; i < DD; i++) mean += part[0][i];
      mean *= (1.0f / DD);
      float var = 0.f;
      for (int i = 0; i < DD; i++) { float t = part[0][i] - mean; var += t * t; }
      var *= (1.0f / DD);
      xr[tid] = (part[0][tid] - mean) * rsqrtf(var + 1e-5f) * ln_w[tid] + ln_b[tid];
    }
  } else {
    if (tid < DD) xr[tid] = ln_b[tid];
  }
  __syncthreads();
  float sk = 0.f, sv = 0.f;
  for (int e = c * 64; e < c * 64 + 64; e++) {
    float xe = xr[e];
    sk += xe * w1[e * DD + d];   // w1 = sWk
    sv += xe * w2[e * DD + d];   // w2 = sWv
  }
  pk[c][d] = sk; pv[c][d] = sv;
  __syncthreads();
  if (tid < DD) {
    float k = pk[0][tid] + pk[1][tid] + sbk[tid];
    float v = pv[0][tid] + pv[1][tid] + sbv[tid];
    KCb[r * DD + tid] = f2b(k);
    VCb[r * DD + tid] = f2b(v);
  }
}

// ---- LayerNorm rows -> bf16 ---- grid(ceil(nrows/4)) block(256)
// mode 0: src rows; 1: spatial visual gather (src=query); 2: virtual-XB (aux=query for frame-0 rows);
// 3: MLP (aux=CLSA[2][128] for frame-0 rows).
__global__ void k_ln(const float* __restrict__ src, const float* __restrict__ aux,
                     u16* __restrict__ dst,
                     const float* __restrict__ w, const float* __restrict__ bb,
                     int nrows, int mode) {
  int wid = (blockIdx.x * blockDim.x + threadIdx.x) >> 6;
  int lane = threadIdx.x & 63;
  if (wid >= nrows) return;
  const float* sp;
  if (mode == 1) { int b2 = wid / (TT * HWW); int r = wid - b2 * (TT * HWW);
                   sp = src + ((size_t)b2 * TP * HWW + HWW + r) * DD; }
  else if (mode == 2) { int b2 = wid / (TP * HWW); int loc = wid - b2 * (TP * HWW);
                        sp = (loc < HWW ? aux : src) + (size_t)wid * DD; }
  else if (mode == 3) { int b2 = wid / (TP * HWW); int loc = wid - b2 * (TP * HWW);
                        sp = (loc < HWW) ? (aux + b2 * DD) : (src + (size_t)wid * DD); }
  else sp = src + (size_t)wid * DD;
  float x0 = sp[lane], x1 = sp[lane + 64];
  float mean = wsum64(x0 + x1) * (1.0f / DD);
  float d0 = x0 - mean, d1 = x1 - mean;
  float var = wsum64(d0 * d0 + d1 * d1) * (1.0f / DD);
  float inv = rsqrtf(var + 1e-5f);
  u16* dp = dst + (size_t)wid * DD;
  dp[lane]      = f2b(d0 * inv * w[lane] + bb[lane]);
  dp[lane + 64] = f2b(d1 * inv * w[lane + 64] + bb[lane + 64]);
}

// ---- MFMA bf16 GEMM, BM=64 BN=128, K=128. A staged in LDS (1 barrier);
// B fragments hoisted from global into registers (launch_bounds(256,2) -> VGPR cap 256
// so the compiler can afford to keep them live instead of sinking the loads).
// outmode 1: scatter orow = b*T_*HW + HW + (r%(T*HW)).
// rm: 0 none; 1 resid[orow*ldc+c]; 2 virtual-XB resid (resid2=query for frame-0 rows).
__global__ __launch_bounds__(256, 2) void k_gemm(
    const u16* __restrict__ A,
    const u16* __restrict__ Wt, const float* __restrict__ bias,
    float* __restrict__ Cf, u16* __restrict__ Cb, int ldc,
    const float* __restrict__ resid, const float* __restrict__ resid2,
    int outmode, int rm) {
  __shared__ __align__(16) u16 As[64 * 128];
  int tx = threadIdx.x;
  int row0 = blockIdx.x * 64, col0 = blockIdx.y * 128;
  int lane = tx & 63, wid = tx >> 6;

  // issue A staging (global -> LDS via regs)
#pragma unroll
  for (int t = 0; t < 4; t++) {
    int c = tx + t * 256;            // 0..1023
    int r = c >> 4, c16 = c & 15;
    int dst = (r * 256 + c16 * 16) ^ ((r & 7) << 4);
    *(uint4*)((char*)As + dst) = *(const uint4*)&A[(size_t)(row0 + r) * 128 + c16 * 8];
  }

  // hoist all 16 B fragments (L1/L2-resident weights); latency overlaps barrier drain
  bf16x8 bw[4][4];
#pragma unroll
  for (int kc = 0; kc < 4; kc++) {
    int ko = kc * 32 + (lane >> 4) * 8;
#pragma unroll
    for (int j = 0; j < 4; j++) {
      int rb = col0 + (wid & 1) * 64 + j * 16 + (lane & 15);
      bw[kc][j] = *(const bf16x8*)&Wt[(size_t)rb * 128 + ko];
    }
  }
  __syncthreads();

  // hoist all 8 A fragments from LDS
  bf16x8 aw[4][2];
#pragma unroll
  for (int kc = 0; kc < 4; kc++) {
    int kob = (kc * 32 + (lane >> 4) * 8) * 2;
#pragma unroll
    for (int i = 0; i < 2; i++) {
      int ra = (wid >> 1) * 32 + i * 16 + (lane & 15);
      aw[kc][i] = *(const bf16x8*)((const char*)As + ((ra * 256 + kob) ^ ((ra & 7) << 4)));
    }
  }

  f32x4 z = {0.f, 0.f, 0.f, 0.f};
  f32x4 acc[2][4];
#pragma unroll
  for (int i = 0; i < 2; i++)
#pragma unroll
    for (int j = 0; j < 4; j++) acc[i][j] = z;
#pragma unroll
  for (int kc = 0; kc < 4; kc++)
#pragma unroll
    for (int i = 0; i < 2; i++)
#pragma unroll
      for (int j = 0; j < 4; j++)
        acc[i][j] = __builtin_amdgcn_mfma_f32_16x16x32_bf16(aw[kc][i], bw[kc][j], acc[i][j], 0, 0, 0);

  int rbase = row0 + (wid >> 1) * 32 + (lane >> 4) * 4;
  int cbase = col0 + (wid & 1) * 64 + (lane & 15);
#pragma unroll
  for (int i = 0; i < 2; i++) {
#pragma unroll
    for (int e = 0; e < 4; e++) {
      int r = rbase + i * 16 + e;
      size_t orow = r;
      if (outmode == 1) { int b2 = r / (TT * HWW); int rr = r - b2 * (TT * HWW);
                          orow = (size_t)b2 * TP * HWW + HWW + rr; }
#pragma unroll
      for (int j = 0; j < 4; j++) {
        int c = cbase + j * 16;
        float v = acc[i][j][e] + bias[c];
        size_t oidx = orow * (size_t)ldc + c;
        if (rm == 1) v += resid[oidx];
        else if (rm == 2) { int b2 = (int)(orow / (TP * HWW)); int loc = (int)orow - b2 * (TP * HWW);
                            v += (loc < HWW ? resid2 : resid)[oidx]; }
        if (Cf) Cf[oidx] = v; else Cb[oidx] = f2b(v);
      }
    }
  }
}

// ---- fused MLP: out0 = resid + (gelu(A@W1+b1))@W2 + b2 ---- grid(306) block(256)
// launch_bounds(256,1): LDS (80KB) already caps residency at 2 blocks/CU, so let the
// register allocator use the full file — keeps hoisted W fragments live (no load sinking).
// Phase-1 W loads are software-prefetched one nb-block ahead (overlap the GELU chain).
__global__ __launch_bounds__(256, 1) void k_mlp(
    const u16* __restrict__ A,
    const u16* __restrict__ W1t, const float* __restrict__ b1,
    const u16* __restrict__ W2t, const float* __restrict__ b2,
    const float* __restrict__ X2, const float* __restrict__ CLSA,
    float* __restrict__ out0) {
  __shared__ __align__(16) u16 As[64 * 128];     // 16 KB
  __shared__ __align__(16) u16 Hs[64 * 512];     // 64 KB, row stride 1024B, swizzled
  int tx = threadIdx.x;
  int row0 = blockIdx.x * 64;
  int lane = tx & 63, wid = tx >> 6;
  f32x4 z = {0.f, 0.f, 0.f, 0.f};

  // stage A (64x128)
#pragma unroll
  for (int t = 0; t < 4; t++) {
    int c = tx + t * 256;
    int r = c >> 4, c16 = c & 15;
    int dst = (r * 256 + c16 * 16) ^ ((r & 7) << 4);
    *(uint4*)((char*)As + dst) = *(const uint4*)&A[(size_t)(row0 + r) * 128 + c16 * 8];
  }

  // prefetch nb=0 W1 fragments (overlaps A-stage drain)
  bf16x8 bw[4][4];
#pragma unroll
  for (int kc = 0; kc < 4; kc++) {
    int ko = kc * 32 + (lane >> 4) * 8;
#pragma unroll
    for (int j = 0; j < 4; j++) {
      int rb = (wid & 1) * 64 + j * 16 + (lane & 15);
      bw[kc][j] = *(const bf16x8*)&W1t[(size_t)rb * 128 + ko];
    }
  }
  __syncthreads();

  // hoist A fragments once (invariant across nb)
  bf16x8 aw[4][2];
#pragma unroll
  for (int kc = 0; kc < 4; kc++) {
    int kob = (kc * 32 + (lane >> 4) * 8) * 2;
#pragma unroll
    for (int i = 0; i < 2; i++) {
      int ra = (wid >> 1) * 32 + i * 16 + (lane & 15);
      aw[kc][i] = *(const bf16x8*)((const char*)As + ((ra * 256 + kob) ^ ((ra & 7) << 4)));
    }
  }

  // ---- phase 1: H = gelu(A @ W1 + b1), 4 col-blocks of 128, prefetch depth 1 ----
#pragma unroll 1
  for (int nb = 0; nb < 4; nb++) {
    f32x4 acc[2][4];
#pragma unroll
    for (int i = 0; i < 2; i++)
#pragma unroll
      for (int j = 0; j < 4; j++) acc[i][j] = z;
#pragma unroll
    for (int kc = 0; kc < 4; kc++)
#pragma unroll
      for (int i = 0; i < 2; i++)
#pragma unroll
        for (int j = 0; j < 4; j++)
          acc[i][j] = __builtin_amdgcn_mfma_f32_16x16x32_bf16(aw[kc][i], bw[kc][j], acc[i][j], 0, 0, 0);
    // prefetch next nb's W1 fragments (latency hides under GELU below)
    if (nb < 3) {
#pragma unroll
      for (int kc = 0; kc < 4; kc++) {
        int ko = kc * 32 + (lane >> 4) * 8;
#pragma unroll
        for (int j = 0; j < 4; j++) {
          int rb = (nb + 1) * 128 + (wid & 1) * 64 + j * 16 + (lane & 15);
          bw[kc][j] = *(const bf16x8*)&W1t[(size_t)rb * 128 + ko];
        }
      }
    }
    // gelu + write to Hs
    int rb0 = (wid >> 1) * 32 + (lane >> 4) * 4;
    int cb0 = nb * 128 + (wid & 1) * 64 + (lane & 15);
#pragma unroll
    for (int i = 0; i < 2; i++)
#pragma unroll
      for (int e = 0; e < 4; e++) {
        int hr = rb0 + i * 16 + e;
#pragma unroll
        for (int j = 0; j < 4; j++) {
          int hc = cb0 + j * 16;
          float v = acc[i][j][e] + b1[hc];
          v = 0.5f * v * (1.0f + erff(v * 0.70710678118654752f));
          *(u16*)((char*)Hs + ((hr * 1024 + hc * 2) ^ ((hr & 7) << 4))) = f2b(v);
        }
      }
  }
  __syncthreads();   // Hs complete

  // ---- phase 2: C = Hs @ W2 + b2 + resid, no barriers ----
  f32x4 acc2[2][4];
#pragma unroll
  for (int i = 0; i < 2; i++)
#pragma unroll
    for (int j = 0; j < 4; j++) acc2[i][j] = z;
#pragma unroll 1
  for (int kb = 0; kb < 4; kb++) {
    bf16x8 bw2[4][4];
#pragma unroll
    for (int kc = 0; kc < 4; kc++) {
      int kcol = kb * 128 + kc * 32 + (lane >> 4) * 8;
#pragma unroll
      for (int j = 0; j < 4; j++) {
        int rb = (wid & 1) * 64 + j * 16 + (lane & 15);
        bw2[kc][j] = *(const bf16x8*)&W2t[(size_t)rb * 512 + kcol];
      }
    }
    bf16x8 ah[4][2];
#pragma unroll
    for (int kc = 0; kc < 4; kc++) {
      int kcol = kb * 128 + kc * 32 + (lane >> 4) * 8;
#pragma unroll
      for (int i = 0; i < 2; i++) {
        int ra = (wid >> 1) * 32 + i * 16 + (lane & 15);
        ah[kc][i] = *(const bf16x8*)((const char*)Hs + ((ra * 1024 + kcol * 2) ^ ((ra & 7) << 4)));
      }
    }
#pragma unroll
    for (int kc = 0; kc < 4; kc++)
#pragma unroll
      for (int i = 0; i < 2; i++)
#pragma unroll
        for (int j = 0; j < 4; j++)
          acc2[i][j] = __builtin_amdgcn_mfma_f32_16x16x32_bf16(ah[kc][i], bw2[kc][j], acc2[i][j], 0, 0, 0);
  }

  int rbase = row0 + (wid >> 1) * 32 + (lane >> 4) * 4;
  int cbase = (wid & 1) * 64 + (lane & 15);
#pragma unroll
  for (int i = 0; i < 2; i++)
#pragma unroll
    for (int e = 0; e < 4; e++) {
      int r = rbase + i * 16 + e;
      int b2i = r / (TP * HWW); int loc = r - b2i * (TP * HWW);
#pragma unroll
      for (int j = 0; j < 4; j++) {
        int c = cbase + j * 16;
        float v = acc2[i][j][e] + b2[c];
        v += (loc < HWW) ? CLSA[b2i * DD + c] : X2[(size_t)r * DD + c];
        out0[(size_t)r * DD + c] = v;
      }
    }
}

// ---- spatial local-window attention: 32-lane group per (pixel, head) ---- grid(9216) block(256)
// FAITHFUL MASK BUG: kv col j (j<25) masked by kernel-pos-j validity (col0=CLS!, col j=neigh j-1);
// col 25 (neigh 24) never masked. Invalid neighbors use pad row = proj(LN(0)).
__global__ __launch_bounds__(256) void k_sattn(const u16* __restrict__ qkvb,
                                               const u16* __restrict__ KCb,
                                               const u16* __restrict__ VCb,
                                               u16* __restrict__ outb) {
  __shared__ float Ps[8][32];
  int tid = threadIdx.x;
  int g = tid >> 5, lj = tid & 31;
  int G = blockIdx.x * 8 + g;
  int n = G >> 2, h = G & 3;
  int f = n / HWW, hw = n - f * HWW;
  int hp = hw / WW_, wp = hw - hp * WW_;
  size_t FB = (size_t)f * HWW * 384;

  const u16* kp;
  bool masked;
  if (lj == 0) {
    kp = KCb + (n & 1) * DD + h * 32;
    masked = !(hp >= 2 && wp >= 2);
  } else {
    int k = lj - 1;
    int y = hp + k / 5 - 2, x = wp + k % 5 - 2;
    bool vok = ((unsigned)y < 24u) & ((unsigned)x < 24u) & (k < 25);
    kp = vok ? (qkvb + FB + (size_t)(y * WW_ + x) * 384 + 128 + h * 32)
             : (KCb + BB * DD + h * 32);
    if (lj < 25) { int ym = hp + lj / 5 - 2, xm = wp + lj % 5 - 2;
                   masked = !(((unsigned)ym < 24u) & ((unsigned)xm < 24u)); }
    else masked = false;
  }
  const uint4* q4p = (const uint4*)(qkvb + (size_t)n * 384 + h * 32);
  const uint4* k4p = (const uint4*)kp;
  float s = 0.f;
#pragma unroll
  for (int i = 0; i < 4; i++) s += dot8p(q4p[i], k4p[i]);

  float scr = masked ? -1e9f : s * SCALE;
  if (lj >= 26) scr = -1e30f;
  float mx = scr;
#pragma unroll
  for (int o = 16; o > 0; o >>= 1) mx = fmaxf(mx, __shfl_xor(mx, o, 32));
  float p = __expf(scr - mx);
  float sum = p;
#pragma unroll
  for (int o = 16; o > 0; o >>= 1) sum += __shfl_xor(sum, o, 32);
  Ps[g][lj] = p * (1.0f / sum);

  float4 P4[7];
#pragma unroll
  for (int i = 0; i < 7; i++) P4[i] = *(const float4*)&Ps[g][i * 4];

  float o = getp(P4, 0) * b2f(VCb[(n & 1) * DD + h * 32 + lj]);
#pragma unroll
  for (int k = 0; k < 25; k++) {
    int y = hp + k / 5 - 2, x = wp + k % 5 - 2;
    bool vok = ((unsigned)y < 24u) & ((unsigned)x < 24u);
    const u16* vp = vok ? (qkvb + FB + (size_t)(y * WW_ + x) * 384 + 256)
                        : (VCb + BB * DD);
    o += getp(P4, k + 1) * b2f(vp[h * 32 + lj]);
  }
  outb[(size_t)n * DD + h * 32 + lj] = f2b(o);
}

// ---- temporal attention, lane-local dots, bf16 QKV ---- grid(576) block(256)
__global__ __launch_bounds__(256) void k_tattn(const u16* __restrict__ qkv,
                                               u16* __restrict__ outb,
                                               float* __restrict__ logits) {
  __shared__ float Qs[8][TP][32];
  __shared__ float Ps[8][TP][17];
  int tid = threadIdx.x;
  int g = tid >> 5, lj = tid & 31;
  int s = blockIdx.x * 2 + (g >> 2);
  int h = g & 3;
  int b = s / HWW, hw = s - b * HWW;
  size_t base = ((size_t)b * TP * HWW + hw) * 384 + h * 32;
  const size_t TSTR = (size_t)HWW * 384;

  float kreg[32];
  {
    const uint4* k4 = (const uint4*)(qkv + base + (size_t)(lj < 17 ? lj : 16) * TSTR + 128);
#pragma unroll
    for (int i = 0; i < 4; i++) {
      uint4 u = k4[i];
      kreg[i * 8 + 0] = blo(u.x); kreg[i * 8 + 1] = bhi(u.x);
      kreg[i * 8 + 2] = blo(u.y); kreg[i * 8 + 3] = bhi(u.y);
      kreg[i * 8 + 4] = blo(u.z); kreg[i * 8 + 5] = bhi(u.z);
      kreg[i * 8 + 6] = blo(u.w); kreg[i * 8 + 7] = bhi(u.w);
    }
  }
  float vreg[TP];
#pragma unroll
  for (int t = 0; t < TP; t++) {
    Qs[g][t][lj] = b2f(qkv[base + (size_t)t * TSTR + lj]);
    vreg[t]      = b2f(qkv[base + (size_t)t * TSTR + 256 + lj]);
  }

  float* lp = logits + (size_t)s * (NHH * TP * TP) + (size_t)h * (TP * TP);
#pragma unroll 4
  for (int tq = 0; tq < TP; tq++) {
    const float4* qrow = (const float4*)&Qs[g][tq][0];
    float a0 = 0.f, a1 = 0.f, a2 = 0.f, a3 = 0.f;
#pragma unroll
    for (int d4 = 0; d4 < 8; d4++) {
      float4 q4 = qrow[d4];
      a0 += q4.x * kreg[d4 * 4 + 0];
      a1 += q4.y * kreg[d4 * 4 + 1];
      a2 += q4.z * kreg[d4 * 4 + 2];
      a3 += q4.w * kreg[d4 * 4 + 3];
    }
    float sc = ((a0 + a1) + (a2 + a3)) * SCALE;
    if (lj < 17) lp[tq * 17 + lj] = sc;
    float scm = (lj < 17) ? sc : -1e30f;
    float mx = scm;
#pragma unroll
    for (int o = 16; o > 0; o >>= 1) mx = fmaxf(mx, __shfl_xor(mx, o, 32));
    float p = __expf(scm - mx);
    float sum = p;
#pragma unroll
    for (int o = 16; o > 0; o >>= 1) sum += __shfl_xor(sum, o, 32);
    if (lj < 17) Ps[g][tq][lj] = p * (1.0f / sum);
  }
#pragma unroll 4
  for (int tq = 0; tq < TP; tq++) {
    const float* prow = &Ps[g][tq][0];
    float o = 0.f;
#pragma unroll
    for (int t = 0; t < TP; t++) o += prow[t] * vreg[t];
    size_t r = ((size_t)b * TP + tq) * HWW + hw;
    outb[r * DD + h * 32 + lj] = f2b(o);
  }
}

// ---- CLS average (frame 0 of X2) -> CLSA[2][128] ---- grid(2) block(256)
__global__ void k_clsavg(const float* __restrict__ x2, float* __restrict__ clsa) {
  __shared__ float part[2][DD];
  int b = blockIdx.x, tid = threadIdx.x;
  int c = tid >> 7, d = tid & 127;
  const float* base = x2 + (size_t)b * TP * HWW * DD;
  float s = 0.f;
  for (int hw = c * 288; hw < c * 288 + 288; ++hw) s += base[(size_t)hw * DD + d];
  part[c][d] = s;
  __syncthreads();
  if (tid < DD) clsa[b * DD + tid] = (part[0][tid] + part[1][tid]) * (1.0f / HWW);
}

extern "C" void kernel_launch(void* const* d_in, const int* in_sizes, int n_in,
                              void* d_out, int out_size, void* d_ws, size_t ws_size,
                              hipStream_t stream) {
  const float* query  = (const float*)d_in[0];
  const float* ln_s_w = (const float*)d_in[3];
  const float* ln_s_b = (const float*)d_in[4];
  const float* sWq = (const float*)d_in[5];  const float* sbq = (const float*)d_in[6];
  const float* sWk = (const float*)d_in[7];  const float* sbk = (const float*)d_in[8];
  const float* sWv = (const float*)d_in[9];  const float* sbv = (const float*)d_in[10];
  const float* sWo = (const float*)d_in[11]; const float* sbo = (const float*)d_in[12];
  const float* ln_t_w = (const float*)d_in[13];
  const float* ln_t_b = (const float*)d_in[14];
  const float* tWq = (const float*)d_in[15]; const float* tbq = (const float*)d_in[16];
  const float* tWk = (const float*)d_in[17]; const float* tbk = (const float*)d_in[18];
  const float* tWv = (const float*)d_in[19]; const float* tbv = (const float*)d_in[20];
  const float* tWo = (const float*)d_in[21]; const float* tbo = (const float*)d_in[22];
  const float* ln_m_w = (const float*)d_in[23];
  const float* ln_m_b = (const float*)d_in[24];
  const float* mW1 = (const float*)d_in[25]; const float* mb1 = (const float*)d_in[26];
  const float* mW2 = (const float*)d_in[27]; const float* mb2 = (const float*)d_in[28];

  float* ws = (float*)d_ws;
  u16*   QKVb = (u16*)ws;                            // bf16, NTOK*384
  u16*   S0b  = (u16*)(ws + 7520256);                // bf16, NTOK*128 (LN / attn outputs)
  float* XB   = ws + 8773632;                        // f32, NTOK*128 (visual rows only)
  float* X2   = ws + 11280384;                       // f32, NTOK*128
  u16*   WT   = (u16*)(ws + 13787136);               // bf16 packed weights (262,144)
  float* sb3  = ws + 13918208;                       // 384
  float* tb3  = ws + 13918592;                       // 384
  u16*   KCb  = (u16*)(ws + 13920000);               // 3*128 bf16
  u16*   VCb  = (u16*)(ws + 13920192);               // 3*128 bf16
  float* CLSA = ws + 13920384;                       // 2*128 f32

  float* out0   = (float*)d_out;
  float* logits = out0 + OUT0_SIZE;

  // 1. pack weights + CLS prep
  k_packprep<<<1030, 256, 0, stream>>>(sWq, sWk, sWv, sWo, tWq, tWk, tWv, tWo, mW1, mW2,
                                       sbq, sbk, sbv, tbq, tbk, tbv,
                                       query, ln_s_w, ln_s_b, WT, sb3, tb3, KCb, VCb);
  // 2. spatial LN (visual gather)
  k_ln<<<NPIX / 4, 256, 0, stream>>>(query, nullptr, S0b, ln_s_w, ln_s_b, NPIX, 1);
  // 3. spatial QKV
  k_gemm<<<dim3(NPIX / 64, 3), 256, 0, stream>>>(S0b, WT, sb3, nullptr, QKVb, 384,
                                                 nullptr, nullptr, 0, 0);
  // 4. spatial attention
  k_sattn<<<NPIX * NHH / 8, 256, 0, stream>>>(QKVb, KCb, VCb, S0b);
  // 5. sWo projection + query residual -> XB (visual rows, scattered)
  k_gemm<<<dim3(NPIX / 64, 1), 256, 0, stream>>>(S0b, WT + 49152, sbo, XB, nullptr, 128,
                                                 query, nullptr, 1, 1);
  // 6. temporal LN (virtual-XB)
  k_ln<<<NTOK / 4, 256, 0, stream>>>(XB, query, S0b, ln_t_w, ln_t_b, NTOK, 2);
  // 7. temporal QKV
  k_gemm<<<dim3(NTOK / 64, 3), 256, 0, stream>>>(S0b, WT + 65536, tb3, nullptr, QKVb, 384,
                                                 nullptr, nullptr, 0, 0);
  // 8. temporal attention (+ logits)
  k_tattn<<<BB * HWW / 2, 256, 0, stream>>>(QKVb, S0b, logits);
  // 9. tWo projection + virtual-XB residual -> X2
  k_gemm<<<dim3(NTOK / 64, 1), 256, 0, stream>>>(S0b, WT + 114688, tbo, X2, nullptr, 128,
                                                 XB, query, 0, 2);
  // 10. CLS average -> CLSA
  k_clsavg<<<2, 256, 0, stream>>>(X2, CLSA);
  // 11. MLP LN (frame-0 rows from CLSA)
  k_ln<<<NTOK / 4, 256, 0, stream>>>(X2, CLSA, S0b, ln_m_w, ln_m_b, NTOK, 3);
  // 12. fused MLP -> out0
  k_mlp<<<NTOK / 64, 256, 0, stream>>>(S0b, WT + 131072, mb1, WT + 196608, mb2,
                                       X2, CLSA, out0);
}

// Round 12
// 199.541 us; speedup vs baseline: 1.0557x; 1.0280x over previous
//
#include <hip/hip_runtime.h>
#include <math.h>

// ---- problem constants ----
#define BB    2
#define TT    16
#define TP    17          // T_ = T+1
#define HH_   24
#define WW_   24
#define HWW   576         // HH*WW
#define DD    128
#define NHH   4
#define MLPD_ 512
#define NPIX  18432       // B*T*HW
#define NTOK  19584       // B*T_*HW
#define SCALE 0.17677669529663688f   // 1/sqrt(32)
#define OUT0_SIZE 2506752            // B*T_*HW*D

typedef unsigned short u16;
typedef __bf16 bf16x8 __attribute__((ext_vector_type(8)));
typedef float f32x4 __attribute__((ext_vector_type(4)));

__device__ __forceinline__ u16 f2b(float f) {
  unsigned u = __float_as_uint(f);
  u += 0x7FFFu + ((u >> 16) & 1u);
  return (u16)(u >> 16);
}
__device__ __forceinline__ float blo(unsigned u) { return __uint_as_float(u << 16); }
__device__ __forceinline__ float bhi(unsigned u) { return __uint_as_float(u & 0xFFFF0000u); }
__device__ __forceinline__ float b2f(u16 u) { return __uint_as_float((unsigned)u << 16); }

__device__ __forceinline__ float dot8p(uint4 a, uint4 b) {
  float s = blo(a.x) * blo(b.x) + bhi(a.x) * bhi(b.x);
  s += blo(a.y) * blo(b.y) + bhi(a.y) * bhi(b.y);
  s += blo(a.z) * blo(b.z) + bhi(a.z) * bhi(b.z);
  s += blo(a.w) * blo(b.w) + bhi(a.w) * bhi(b.w);
  return s;
}
__device__ __forceinline__ float getp(const float4* P, int j) {
  float4 v = P[j >> 2];
  switch (j & 3) { case 0: return v.x; case 1: return v.y; case 2: return v.z; default: return v.w; }
}

__device__ __forceinline__ float wsum64(float v) {
#pragma unroll
  for (int o = 32; o > 0; o >>= 1) v += __shfl_xor(v, o, 64);
  return v;
}

// async global->LDS, 16B per lane, no dest register (loads can't be serialized by scheduler)
__device__ __forceinline__ void gld_lds16(const void* g, void* l) {
  __builtin_amdgcn_global_load_lds(
      (const __attribute__((address_space(1))) void*)g,
      (__attribute__((address_space(3))) void*)l, 16, 0, 0);
}

// ---- pack weights/biases (blocks 0..1026) + CLS prep (blocks 1027..1029) ---- grid(1030) block(256)
__global__ void k_packprep(const float* w0, const float* w1, const float* w2, const float* w3,
                           const float* w4, const float* w5, const float* w6, const float* w7,
                           const float* w8, const float* w9,
                           const float* sbq, const float* sbk, const float* sbv,
                           const float* tbq, const float* tbk, const float* tbv,
                           const float* query, const float* ln_w, const float* ln_b,
                           u16* __restrict__ out, float* __restrict__ sb3, float* __restrict__ tb3,
                           u16* __restrict__ KCb, u16* __restrict__ VCb) {
  int bid = blockIdx.x, tid = threadIdx.x;
  if (bid < 1027) {
    int idx = bid * 256 + tid;
    if (idx < 262144) {
      if (idx < 131072) {
        int seg = idx >> 14, local = idx & 16383;
        const float* tbl[8] = {w0, w1, w2, w3, w4, w5, w6, w7};
        int nn = local >> 7, kk = local & 127;
        out[idx] = f2b(tbl[seg][(size_t)kk * 128 + nn]);
      } else if (idx < 196608) {
        int local = idx - 131072;
        int nn = local >> 7, kk = local & 127;
        out[idx] = f2b(w8[(size_t)kk * 512 + nn]);
      } else {
        int local = idx - 196608;
        int nn = local >> 9, kk = local & 511;
        out[idx] = f2b(w9[(size_t)kk * 128 + nn]);
      }
    } else if (idx < 262528) {
      int i = idx - 262144;
      sb3[i] = i < 128 ? sbq[i] : (i < 256 ? sbk[i - 128] : sbv[i - 256]);
    } else if (idx < 262912) {
      int i = idx - 262528;
      tb3[i] = i < 128 ? tbq[i] : (i < 256 ? tbk[i - 128] : tbv[i - 256]);
    }
    return;
  }
  __shared__ float part[2][DD];
  __shared__ float xr[DD];
  __shared__ float pk[2][DD], pv[2][DD];
  int r = bid - 1027;
  int c = tid >> 7, d = tid & 127;
  if (r < BB) {
    const float* base = query + (size_t)r * TP * HWW * DD + d;   // frame 0
    float s = 0.f;
    for (int hw = c * 288; hw < c * 288 + 288; ++hw) s += base[(size_t)hw * DD];
    part[c][d] = s;
    __syncthreads();
    if (tid < DD) part[0][tid] = (part[0][tid] + part[1][tid]) * (1.0f / HWW);
    __syncthreads();
    if (tid < DD) {
      float mean = 0.f;
      for (int i = 0; i < DD; i++) mean += part[0][i];
      mean *= (1.0f / DD);
      float var = 0.f;
      for (int i = 0; i < DD; i++) { float t = part[0][i] - mean; var += t * t; }
      var *= (1.0f / DD);
      xr[tid] = (part[0][tid] - mean) * rsqrtf(var + 1e-5f) * ln_w[tid] + ln_b[tid];
    }
  } else {
    if (tid < DD) xr[tid] = ln_b[tid];
  }
  __syncthreads();
  float sk = 0.f, sv = 0.f;
  for (int e = c * 64; e < c * 64 + 64; e++) {
    float xe = xr[e];
    sk += xe * w1[e * DD + d];   // w1 = sWk
    sv += xe * w2[e * DD + d];   // w2 = sWv
  }
  pk[c][d] = sk; pv[c][d] = sv;
  __syncthreads();
  if (tid < DD) {
    float k = pk[0][tid] + pk[1][tid] + sbk[tid];
    float v = pv[0][tid] + pv[1][tid] + sbv[tid];
    KCb[r * DD + tid] = f2b(k);
    VCb[r * DD + tid] = f2b(v);
  }
}

// ---- LayerNorm rows -> bf16 ---- grid(ceil(nrows/4)) block(256)
// mode 0: src rows; 1: spatial visual gather (src=query); 2: virtual-XB (aux=query for frame-0 rows);
// 3: MLP (aux=CLSA[2][128] for frame-0 rows).
__global__ void k_ln(const float* __restrict__ src, const float* __restrict__ aux,
                     u16* __restrict__ dst,
                     const float* __restrict__ w, const float* __restrict__ bb,
                     int nrows, int mode) {
  int wid = (blockIdx.x * blockDim.x + threadIdx.x) >> 6;
  int lane = threadIdx.x & 63;
  if (wid >= nrows) return;
  const float* sp;
  if (mode == 1) { int b2 = wid / (TT * HWW); int r = wid - b2 * (TT * HWW);
                   sp = src + ((size_t)b2 * TP * HWW + HWW + r) * DD; }
  else if (mode == 2) { int b2 = wid / (TP * HWW); int loc = wid - b2 * (TP * HWW);
                        sp = (loc < HWW ? aux : src) + (size_t)wid * DD; }
  else if (mode == 3) { int b2 = wid / (TP * HWW); int loc = wid - b2 * (TP * HWW);
                        sp = (loc < HWW) ? (aux + b2 * DD) : (src + (size_t)wid * DD); }
  else sp = src + (size_t)wid * DD;
  float x0 = sp[lane], x1 = sp[lane + 64];
  float mean = wsum64(x0 + x1) * (1.0f / DD);
  float d0 = x0 - mean, d1 = x1 - mean;
  float var = wsum64(d0 * d0 + d1 * d1) * (1.0f / DD);
  float inv = rsqrtf(var + 1e-5f);
  u16* dp = dst + (size_t)wid * DD;
  dp[lane]      = f2b(d0 * inv * w[lane] + bb[lane]);
  dp[lane + 64] = f2b(d1 * inv * w[lane + 64] + bb[lane + 64]);
}

// ---- MFMA bf16 GEMM, BM=64 BN=128, BK=128 stages via global_load_lds (async, no dest reg:
// all 12 staging loads in flight together, ONE latency exposure per stage).
// LDS swizzle via pre-swizzled global source (linear LDS dest + inverse-swizzle src = rule 21).
// outmode 1: scatter orow = b*T_*HW + HW + (r%(T*HW)).
// rm: 0 none; 1 resid; 2 virtual-XB (resid2=query frame-0); 3 CLSA (resid2=CLSA frame-0).
// gelu: exact GELU before residual. Cb!=null -> bf16 out, else Cf f32.
__global__ __launch_bounds__(256, 2) void k_gemm(
    const u16* __restrict__ A, int K,
    const u16* __restrict__ Wt, const float* __restrict__ bias,
    float* __restrict__ Cf, u16* __restrict__ Cb, int ldc,
    const float* __restrict__ resid, const float* __restrict__ resid2,
    int outmode, int rm, int gelu) {
  __shared__ __align__(16) u16 As[64 * 128];     // 16 KB, swizzled image
  __shared__ __align__(16) u16 Bs[128 * 128];    // 32 KB, swizzled image
  int tx = threadIdx.x;
  int row0 = blockIdx.x * 64, col0 = blockIdx.y * 128;
  int lane = tx & 63, wid = tx >> 6;
  f32x4 z = {0.f, 0.f, 0.f, 0.f};
  f32x4 acc[2][4];
#pragma unroll
  for (int i = 0; i < 2; i++)
#pragma unroll
    for (int j = 0; j < 4; j++) acc[i][j] = z;

  for (int k0 = 0; k0 < K; k0 += 128) {
    if (k0) __syncthreads();
    // stage A: 1024 16B-chunks; LDS linear, source pre-swizzled
#pragma unroll
    for (int t = 0; t < 4; t++) {
      int ci = t * 256 + tx;
      int r = ci >> 4;
      int c16 = (ci ^ (r & 7)) & 15;
      gld_lds16(&A[(size_t)(row0 + r) * K + k0 + c16 * 8], (char*)As + ci * 16);
    }
    // stage B: 2048 chunks
#pragma unroll
    for (int t = 0; t < 8; t++) {
      int ci = t * 256 + tx;
      int r = ci >> 4;
      int c16 = (ci ^ (r & 7)) & 15;
      gld_lds16(&Wt[(size_t)(col0 + r) * K + k0 + c16 * 8], (char*)Bs + ci * 16);
    }
    __syncthreads();    // drains vmcnt -> one exposure
#pragma unroll
    for (int kc = 0; kc < 4; kc++) {
      int kob = (kc * 32 + (lane >> 4) * 8) * 2;
      bf16x8 af[2], bfr[4];
#pragma unroll
      for (int i = 0; i < 2; i++) {
        int ra = (wid >> 1) * 32 + i * 16 + (lane & 15);
        af[i] = *(const bf16x8*)((const char*)As + ((ra * 256 + kob) ^ ((ra & 7) << 4)));
      }
#pragma unroll
      for (int j = 0; j < 4; j++) {
        int rb = (wid & 1) * 64 + j * 16 + (lane & 15);
        bfr[j] = *(const bf16x8*)((const char*)Bs + ((rb * 256 + kob) ^ ((rb & 7) << 4)));
      }
#pragma unroll
      for (int i = 0; i < 2; i++)
#pragma unroll
        for (int j = 0; j < 4; j++)
          acc[i][j] = __builtin_amdgcn_mfma_f32_16x16x32_bf16(af[i], bfr[j], acc[i][j], 0, 0, 0);
    }
  }

  int rbase = row0 + (wid >> 1) * 32 + (lane >> 4) * 4;
  int cbase = col0 + (wid & 1) * 64 + (lane & 15);
#pragma unroll
  for (int i = 0; i < 2; i++) {
#pragma unroll
    for (int e = 0; e < 4; e++) {
      int r = rbase + i * 16 + e;
      size_t orow = r;
      if (outmode == 1) { int b2 = r / (TT * HWW); int rr = r - b2 * (TT * HWW);
                          orow = (size_t)b2 * TP * HWW + HWW + rr; }
#pragma unroll
      for (int j = 0; j < 4; j++) {
        int c = cbase + j * 16;
        float v = acc[i][j][e] + bias[c];
        if (gelu) v = 0.5f * v * (1.0f + erff(v * 0.70710678118654752f));
        size_t oidx = orow * (size_t)ldc + c;
        if (rm == 1) v += resid[oidx];
        else if (rm == 2) { int b2 = (int)(orow / (TP * HWW)); int loc = (int)orow - b2 * (TP * HWW);
                            v += (loc < HWW ? resid2 : resid)[oidx]; }
        else if (rm == 3) { int b2 = (int)(orow / (TP * HWW)); int loc = (int)orow - b2 * (TP * HWW);
                            v += (loc < HWW) ? resid2[b2 * DD + c] : resid[oidx]; }
        if (Cf) Cf[oidx] = v; else Cb[oidx] = f2b(v);
      }
    }
  }
}

// ---- spatial local-window attention: 32-lane group per (pixel, head) ---- grid(9216) block(256)
// FAITHFUL MASK BUG: kv col j (j<25) masked by kernel-pos-j validity (col0=CLS!, col j=neigh j-1);
// col 25 (neigh 24) never masked. Invalid neighbors use pad row = proj(LN(0)).
__global__ __launch_bounds__(256) void k_sattn(const u16* __restrict__ qkvb,
                                               const u16* __restrict__ KCb,
                                               const u16* __restrict__ VCb,
                                               u16* __restrict__ outb) {
  __shared__ float Ps[8][32];
  int tid = threadIdx.x;
  int g = tid >> 5, lj = tid & 31;
  int G = blockIdx.x * 8 + g;
  int n = G >> 2, h = G & 3;
  int f = n / HWW, hw = n - f * HWW;
  int hp = hw / WW_, wp = hw - hp * WW_;
  size_t FB = (size_t)f * HWW * 384;

  const u16* kp;
  bool masked;
  if (lj == 0) {
    kp = KCb + (n & 1) * DD + h * 32;
    masked = !(hp >= 2 && wp >= 2);
  } else {
    int k = lj - 1;
    int y = hp + k / 5 - 2, x = wp + k % 5 - 2;
    bool vok = ((unsigned)y < 24u) & ((unsigned)x < 24u) & (k < 25);
    kp = vok ? (qkvb + FB + (size_t)(y * WW_ + x) * 384 + 128 + h * 32)
             : (KCb + BB * DD + h * 32);
    if (lj < 25) { int ym = hp + lj / 5 - 2, xm = wp + lj % 5 - 2;
                   masked = !(((unsigned)ym < 24u) & ((unsigned)xm < 24u)); }
    else masked = false;
  }
  const uint4* q4p = (const uint4*)(qkvb + (size_t)n * 384 + h * 32);
  const uint4* k4p = (const uint4*)kp;
  float s = 0.f;
#pragma unroll
  for (int i = 0; i < 4; i++) s += dot8p(q4p[i], k4p[i]);

  float scr = masked ? -1e9f : s * SCALE;
  if (lj >= 26) scr = -1e30f;
  float mx = scr;
#pragma unroll
  for (int o = 16; o > 0; o >>= 1) mx = fmaxf(mx, __shfl_xor(mx, o, 32));
  float p = __expf(scr - mx);
  float sum = p;
#pragma unroll
  for (int o = 16; o > 0; o >>= 1) sum += __shfl_xor(sum, o, 32);
  Ps[g][lj] = p * (1.0f / sum);

  float4 P4[7];
#pragma unroll
  for (int i = 0; i < 7; i++) P4[i] = *(const float4*)&Ps[g][i * 4];

  float o = getp(P4, 0) * b2f(VCb[(n & 1) * DD + h * 32 + lj]);
#pragma unroll
  for (int k = 0; k < 25; k++) {
    int y = hp + k / 5 - 2, x = wp + k % 5 - 2;
    bool vok = ((unsigned)y < 24u) & ((unsigned)x < 24u);
    const u16* vp = vok ? (qkvb + FB + (size_t)(y * WW_ + x) * 384 + 256)
                        : (VCb + BB * DD);
    o += getp(P4, k + 1) * b2f(vp[h * 32 + lj]);
  }
  outb[(size_t)n * DD + h * 32 + lj] = f2b(o);
}

// ---- temporal attention, lane-local dots, bf16 QKV ---- grid(576) block(256)
__global__ __launch_bounds__(256) void k_tattn(const u16* __restrict__ qkv,
                                               u16* __restrict__ outb,
                                               float* __restrict__ logits) {
  __shared__ float Qs[8][TP][32];
  __shared__ float Ps[8][TP][17];
  int tid = threadIdx.x;
  int g = tid >> 5, lj = tid & 31;
  int s = blockIdx.x * 2 + (g >> 2);
  int h = g & 3;
  int b = s / HWW, hw = s - b * HWW;
  size_t base = ((size_t)b * TP * HWW + hw) * 384 + h * 32;
  const size_t TSTR = (size_t)HWW * 384;

  float kreg[32];
  {
    const uint4* k4 = (const uint4*)(qkv + base + (size_t)(lj < 17 ? lj : 16) * TSTR + 128);
#pragma unroll
    for (int i = 0; i < 4; i++) {
      uint4 u = k4[i];
      kreg[i * 8 + 0] = blo(u.x); kreg[i * 8 + 1] = bhi(u.x);
      kreg[i * 8 + 2] = blo(u.y); kreg[i * 8 + 3] = bhi(u.y);
      kreg[i * 8 + 4] = blo(u.z); kreg[i * 8 + 5] = bhi(u.z);
      kreg[i * 8 + 6] = blo(u.w); kreg[i * 8 + 7] = bhi(u.w);
    }
  }
  float vreg[TP];
#pragma unroll
  for (int t = 0; t < TP; t++) {
    Qs[g][t][lj] = b2f(qkv[base + (size_t)t * TSTR + lj]);
    vreg[t]      = b2f(qkv[base + (size_t)t * TSTR + 256 + lj]);
  }

  float* lp = logits + (size_t)s * (NHH * TP * TP) + (size_t)h * (TP * TP);
#pragma unroll 4
  for (int tq = 0; tq < TP; tq++) {
    const float4* qrow = (const float4*)&Qs[g][tq][0];
    float a0 = 0.f, a1 = 0.f, a2 = 0.f, a3 = 0.f;
#pragma unroll
    for (int d4 = 0; d4 < 8; d4++) {
      float4 q4 = qrow[d4];
      a0 += q4.x * kreg[d4 * 4 + 0];
      a1 += q4.y * kreg[d4 * 4 + 1];
      a2 += q4.z * kreg[d4 * 4 + 2];
      a3 += q4.w * kreg[d4 * 4 + 3];
    }
    float sc = ((a0 + a1) + (a2 + a3)) * SCALE;
    if (lj < 17) lp[tq * 17 + lj] = sc;
    float scm = (lj < 17) ? sc : -1e30f;
    float mx = scm;
#pragma unroll
    for (int o = 16; o > 0; o >>= 1) mx = fmaxf(mx, __shfl_xor(mx, o, 32));
    float p = __expf(scm - mx);
    float sum = p;
#pragma unroll
    for (int o = 16; o > 0; o >>= 1) sum += __shfl_xor(sum, o, 32);
    if (lj < 17) Ps[g][tq][lj] = p * (1.0f / sum);
  }
#pragma unroll 4
  for (int tq = 0; tq < TP; tq++) {
    const float* prow = &Ps[g][tq][0];
    float o = 0.f;
#pragma unroll
    for (int t = 0; t < TP; t++) o += prow[t] * vreg[t];
    size_t r = ((size_t)b * TP + tq) * HWW + hw;
    outb[r * DD + h * 32 + lj] = f2b(o);
  }
}

// ---- CLS average (frame 0 of X2) -> CLSA[2][128] ---- grid(2) block(256)
__global__ void k_clsavg(const float* __restrict__ x2, float* __restrict__ clsa) {
  __shared__ float part[2][DD];
  int b = blockIdx.x, tid = threadIdx.x;
  int c = tid >> 7, d = tid & 127;
  const float* base = x2 + (size_t)b * TP * HWW * DD;
  float s = 0.f;
  for (int hw = c * 288; hw < c * 288 + 288; ++hw) s += base[(size_t)hw * DD + d];
  part[c][d] = s;
  __syncthreads();
  if (tid < DD) clsa[b * DD + tid] = (part[0][tid] + part[1][tid]) * (1.0f / HWW);
}

extern "C" void kernel_launch(void* const* d_in, const int* in_sizes, int n_in,
                              void* d_out, int out_size, void* d_ws, size_t ws_size,
                              hipStream_t stream) {
  const float* query  = (const float*)d_in[0];
  const float* ln_s_w = (const float*)d_in[3];
  const float* ln_s_b = (const float*)d_in[4];
  const float* sWq = (const float*)d_in[5];  const float* sbq = (const float*)d_in[6];
  const float* sWk = (const float*)d_in[7];  const float* sbk = (const float*)d_in[8];
  const float* sWv = (const float*)d_in[9];  const float* sbv = (const float*)d_in[10];
  const float* sWo = (const float*)d_in[11]; const float* sbo = (const float*)d_in[12];
  const float* ln_t_w = (const float*)d_in[13];
  const float* ln_t_b = (const float*)d_in[14];
  const float* tWq = (const float*)d_in[15]; const float* tbq = (const float*)d_in[16];
  const float* tWk = (const float*)d_in[17]; const float* tbk = (const float*)d_in[18];
  const float* tWv = (const float*)d_in[19]; const float* tbv = (const float*)d_in[20];
  const float* tWo = (const float*)d_in[21]; const float* tbo = (const float*)d_in[22];
  const float* ln_m_w = (const float*)d_in[23];
  const float* ln_m_b = (const float*)d_in[24];
  const float* mW1 = (const float*)d_in[25]; const float* mb1 = (const float*)d_in[26];
  const float* mW2 = (const float*)d_in[27]; const float* mb2 = (const float*)d_in[28];

  float* ws = (float*)d_ws;
  u16*   QKVb = (u16*)ws;                            // bf16, NTOK*384
  u16*   H1b  = (u16*)ws;                            // bf16 NTOK*512, aliases QKVb (dead by then)
  u16*   S0b  = (u16*)(ws + 7520256);                // bf16, NTOK*128 (LN / attn outputs)
  float* XB   = ws + 8773632;                        // f32, NTOK*128 (visual rows only)
  float* X2   = ws + 11280384;                       // f32, NTOK*128
  u16*   WT   = (u16*)(ws + 13787136);               // bf16 packed weights (262,144)
  float* sb3  = ws + 13918208;                       // 384
  float* tb3  = ws + 13918592;                       // 384
  u16*   KCb  = (u16*)(ws + 13920000);               // 3*128 bf16
  u16*   VCb  = (u16*)(ws + 13920192);               // 3*128 bf16
  float* CLSA = ws + 13920384;                       // 2*128 f32

  float* out0   = (float*)d_out;
  float* logits = out0 + OUT0_SIZE;

  // 1. pack weights + CLS prep
  k_packprep<<<1030, 256, 0, stream>>>(sWq, sWk, sWv, sWo, tWq, tWk, tWv, tWo, mW1, mW2,
                                       sbq, sbk, sbv, tbq, tbk, tbv,
                                       query, ln_s_w, ln_s_b, WT, sb3, tb3, KCb, VCb);
  // 2. spatial LN (visual gather)
  k_ln<<<NPIX / 4, 256, 0, stream>>>(query, nullptr, S0b, ln_s_w, ln_s_b, NPIX, 1);
  // 3. spatial QKV
  k_gemm<<<dim3(NPIX / 64, 3), 256, 0, stream>>>(S0b, 128, WT, sb3, nullptr, QKVb, 384,
                                                 nullptr, nullptr, 0, 0, 0);
  // 4. spatial attention
  k_sattn<<<NPIX * NHH / 8, 256, 0, stream>>>(QKVb, KCb, VCb, S0b);
  // 5. sWo projection + query residual -> XB (visual rows, scattered)
  k_gemm<<<dim3(NPIX / 64, 1), 256, 0, stream>>>(S0b, 128, WT + 49152, sbo, XB, nullptr, 128,
                                                 query, nullptr, 1, 1, 0);
  // 6. temporal LN (virtual-XB)
  k_ln<<<NTOK / 4, 256, 0, stream>>>(XB, query, S0b, ln_t_w, ln_t_b, NTOK, 2);
  // 7. temporal QKV
  k_gemm<<<dim3(NTOK / 64, 3), 256, 0, stream>>>(S0b, 128, WT + 65536, tb3, nullptr, QKVb, 384,
                                                 nullptr, nullptr, 0, 0, 0);
  // 8. temporal attention (+ logits)
  k_tattn<<<BB * HWW / 2, 256, 0, stream>>>(QKVb, S0b, logits);
  // 9. tWo projection + virtual-XB residual -> X2
  k_gemm<<<dim3(NTOK / 64, 1), 256, 0, stream>>>(S0b, 128, WT + 114688, tbo, X2, nullptr, 128,
                                                 XB, query, 0, 2, 0);
  // 10. CLS average -> CLSA
  k_clsavg<<<2, 256, 0, stream>>>(X2, CLSA);
  // 11. MLP LN (frame-0 rows from CLSA)
  k_ln<<<NTOK / 4, 256, 0, stream>>>(X2, CLSA, S0b, ln_m_w, ln_m_b, NTOK, 3);
  // 12. MLP1: gelu(LN(x)@W1+b1) -> H1b (bf16)
  k_gemm<<<dim3(NTOK / 64, 4), 256, 0, stream>>>(S0b, 128, WT + 131072, mb1, nullptr, H1b, 512,
                                                 nullptr, nullptr, 0, 0, 1);
  // 13. MLP2: H@W2+b2 + resid (X2 / CLSA frame-0) -> out0
  k_gemm<<<dim3(NTOK / 64, 1), 256, 0, stream>>>(H1b, 512, WT + 196608, mb2, out0, nullptr, 128,
                                                 X2, CLSA, 0, 3, 0);
}